// Round 4
// baseline (58.227 us; speedup 1.0000x reference)
//
#include <hip/hip_runtime.h>
#include <math.h>

#define B_SZ   2048
#define D_SZ   4096
#define NBASIS 8
#define TB     16            // batch rows per block
#define NC     32            // d-chunks
#define DC     128           // d's per chunk (== blockDim)
#define NBG    (B_SZ / TB)   // 128 batch groups

// ws layout:
//   effc_t : NC*NBASIS*DC float4 = 524288 B  ([c][n][dl], o in .x/.y/.z)
//   effb   : D_SZ float4         =  65536 B
//   partial: NC*B_SZ*3 float     = 786432 B
#define WS_EFFC_BYTES  (NC * NBASIS * DC * 16)
#define WS_EFFB_BYTES  (D_SZ * 16)
#define WS_PART_BYTES  (NC * B_SZ * 3 * 4)

// ---------------------------------------------------------------------------
__global__ __launch_bounds__(256) void precompute_eff(
    const float* __restrict__ coef, const float* __restrict__ sb,
    const float* __restrict__ ssp,  const float* __restrict__ mask,
    float4* __restrict__ effc_t, float4* __restrict__ effb)
{
    int d = blockIdx.x * 256 + threadIdx.x;
    if (d >= D_SZ) return;
    float m0 = mask[d*3+0], m1 = mask[d*3+1], m2 = mask[d*3+2];
    float s0 = ssp[d*3+0]*m0, s1 = ssp[d*3+1]*m1, s2 = ssp[d*3+2]*m2;
    int c  = d / DC;
    int dl = d % DC;
    #pragma unroll
    for (int n = 0; n < NBASIS; ++n) {
        float4 v;
        v.x = coef[(d*3+0)*NBASIS + n] * s0;
        v.y = coef[(d*3+1)*NBASIS + n] * s1;
        v.z = coef[(d*3+2)*NBASIS + n] * s2;
        v.w = 0.0f;
        effc_t[(c*NBASIS + n)*DC + dl] = v;
    }
    float4 bv;
    bv.x = sb[d*3+0]*m0; bv.y = sb[d*3+1]*m1; bv.z = sb[d*3+2]*m2; bv.w = 0.0f;
    effb[d] = bv;
}

// ---------------------------------------------------------------------------
// Main kernel: 128 threads, block (bg, dc) covers b in [bg*TB, +TB), d-chunk dc.
// One d per thread; 16 b's per thread; 16 KB LDS for the coef chunk.
__global__ __launch_bounds__(128) void kan_main(
    const float* __restrict__ x, const float4* __restrict__ effc_t,
    const float4* __restrict__ effb, const float* __restrict__ grid,
    float* __restrict__ partial)
{
    __shared__ float4 effc[NBASIS * DC];   // 16 KB, reused for reduction

    const int tid = threadIdx.x;           // 0..127
    const int bg  = blockIdx.x;            // 0..NBG-1
    const int dc  = blockIdx.y;            // 0..NC-1
    const int d   = dc * DC + tid;

    // stage coef chunk (coalesced 16B/lane)
    #pragma unroll
    for (int i = 0; i < NBASIS; ++i)
        effc[i * DC + tid] = effc_t[(dc * NBASIS + i) * DC + tid];

    const float g3   = grid[3];                     // -1
    const float invh = 1.0f / (grid[4] - grid[3]);  // 2.5
    const float4 eb  = effb[d];
    __syncthreads();

    const int b0 = bg * TB;
    const float* xp = x + (size_t)b0 * D_SZ + d;
    float xv[TB];
    #pragma unroll
    for (int q = 0; q < TB; ++q) xv[q] = xp[(size_t)q * D_SZ];

    float acc[TB][3];
    #pragma unroll
    for (int q = 0; q < TB; ++q) {
        float X = xv[q];
        float u   = (X - g3) * invh;
        float cfl = fminf(fmaxf(truncf(u), 0.0f), 4.0f);
        int   cell = (int)cfl;
        float t  = u - cfl;
        float t2 = t*t, t3 = t2*t;
        float w0 = fmaf(fmaf(fmaf(t, -1.0f/6.0f, 0.5f), t, -0.5f), t, 1.0f/6.0f);
        float w1 = fmaf(fmaf(t, 0.5f, -1.0f), t2, 2.0f/3.0f);
        float w3 = t3 * (1.0f/6.0f);
        float w2 = 1.0f - w0 - w1 - w3;
        float e   = __expf(-X);
        float sil = X * __builtin_amdgcn_rcpf(1.0f + e);

        const float4* cp = &effc[cell * DC + tid];
        float4 k0 = cp[0];
        float4 k1 = cp[DC];
        float4 k2 = cp[2*DC];
        float4 k3 = cp[3*DC];
        acc[q][0] = fmaf(w0,k0.x, fmaf(w1,k1.x, fmaf(w2,k2.x, fmaf(w3,k3.x, sil*eb.x))));
        acc[q][1] = fmaf(w0,k0.y, fmaf(w1,k1.y, fmaf(w2,k2.y, fmaf(w3,k3.y, sil*eb.y))));
        acc[q][2] = fmaf(w0,k0.z, fmaf(w1,k1.z, fmaf(w2,k2.z, fmaf(w3,k3.z, sil*eb.z))));
    }

    // ---- block reduction: LDS transpose (conflict-free) + shuffle butterfly ----
    float* red = (float*)effc;             // 4096 floats capacity; use 24*128
    const int lane = tid & 63;
    const int wv   = tid >> 6;             // 0..1
    #pragma unroll
    for (int half = 0; half < 2; ++half) {
        __syncthreads();                   // WAR on previous LDS use
        #pragma unroll
        for (int q = 0; q < 8; ++q)
            #pragma unroll
            for (int o = 0; o < 3; ++o)
                red[(q*3 + o)*DC + tid] = acc[half*8 + q][o];
        __syncthreads();
        #pragma unroll
        for (int j = 0; j < 12; ++j) {
            int r = wv*12 + j;             // 24 rows / 2 waves
            float s = red[r*DC + lane] + red[r*DC + 64 + lane];
            #pragma unroll
            for (int off = 1; off < 64; off <<= 1)
                s += __shfl_xor(s, off, 64);
            if (lane == 0) {
                int q = half*8 + r/3, o = r % 3;
                partial[((size_t)dc * B_SZ + (b0 + q))*3 + o] = s;
            }
        }
    }
}

// ---------------------------------------------------------------------------
__global__ __launch_bounds__(256) void reduce_partials(
    const float* __restrict__ partial, float* __restrict__ out)
{
    int i = blockIdx.x * 256 + threadIdx.x;
    if (i >= B_SZ * 3) return;
    float s = 0.0f;
    #pragma unroll
    for (int c = 0; c < NC; ++c) s += partial[(size_t)c * B_SZ * 3 + i];
    out[i] = s;
}

// ---------------------------------------------------------------------------
// Fallback (no workspace): block per b, raw arrays. Slower but correct.
__global__ __launch_bounds__(256) void kan_fallback(
    const float* __restrict__ x, const float* __restrict__ grid,
    const float* __restrict__ coef, const float* __restrict__ sb,
    const float* __restrict__ ssp,  const float* __restrict__ mask,
    float* __restrict__ out)
{
    __shared__ float red[3][4];
    int b = blockIdx.x, tid = threadIdx.x;
    float g3 = grid[3], invh = 1.0f / (grid[4] - grid[3]);
    float acc[3] = {0.f, 0.f, 0.f};
    for (int i = 0; i < D_SZ / 256; ++i) {
        int d = i * 256 + tid;
        float xv = x[(size_t)b * D_SZ + d];
        float u  = (xv - g3) * invh;
        float cfl = floorf(u);
        cfl = fminf(fmaxf(cfl, 0.0f), 4.0f);
        int  cell = (int)cfl;
        float t  = u - cfl;
        float t2 = t * t, t3 = t2 * t;
        float omt = 1.0f - t;
        float w0 = omt*omt*omt * (1.0f/6.0f);
        float w1 = (3.0f*t3 - 6.0f*t2 + 4.0f) * (1.0f/6.0f);
        float w2 = (-3.0f*t3 + 3.0f*t2 + 3.0f*t + 1.0f) * (1.0f/6.0f);
        float w3 = t3 * (1.0f/6.0f);
        float sil = xv / (1.0f + __expf(-xv));
        #pragma unroll
        for (int o = 0; o < 3; ++o) {
            const float* cp = &coef[(d*3 + o) * NBASIS + cell];
            float s = w0*cp[0] + w1*cp[1] + w2*cp[2] + w3*cp[3];
            float m = mask[d*3 + o];
            acc[o] += s * ssp[d*3 + o] * m + sil * sb[d*3 + o] * m;
        }
    }
    int lane = tid & 63, wv = tid >> 6;
    #pragma unroll
    for (int o = 0; o < 3; ++o) {
        float v = acc[o];
        #pragma unroll
        for (int off = 32; off >= 1; off >>= 1) v += __shfl_down(v, off, 64);
        if (lane == 0) red[o][wv] = v;
    }
    __syncthreads();
    if (tid < 3) {
        float s = red[tid][0] + red[tid][1] + red[tid][2] + red[tid][3];
        out[b * 3 + tid] = s;
    }
}

// ---------------------------------------------------------------------------
extern "C" void kernel_launch(void* const* d_in, const int* in_sizes, int n_in,
                              void* d_out, int out_size, void* d_ws, size_t ws_size,
                              hipStream_t stream)
{
    const float* x    = (const float*)d_in[0];
    const float* grid = (const float*)d_in[4];
    const float* coef = (const float*)d_in[5];
    const float* sb   = (const float*)d_in[6];
    const float* ssp  = (const float*)d_in[7];
    const float* mask = (const float*)d_in[8];
    float* out = (float*)d_out;

    size_t need = (size_t)WS_EFFC_BYTES + WS_EFFB_BYTES + WS_PART_BYTES;
    if (ws_size >= need) {
        float4* effc_t  = (float4*)d_ws;
        float4* effb    = (float4*)((char*)d_ws + WS_EFFC_BYTES);
        float*  partial = (float*)((char*)d_ws + WS_EFFC_BYTES + WS_EFFB_BYTES);

        precompute_eff<<<D_SZ/256, 256, 0, stream>>>(coef, sb, ssp, mask, effc_t, effb);
        dim3 g(NBG, NC);
        kan_main<<<g, 128, 0, stream>>>(x, effc_t, effb, grid, partial);
        reduce_partials<<<(B_SZ*3 + 255)/256, 256, 0, stream>>>(partial, out);
    } else {
        kan_fallback<<<B_SZ, 256, 0, stream>>>(x, grid, coef, sb, ssp, mask, out);
    }
}

// Round 5
// 33.886 us; speedup vs baseline: 1.7183x; 1.7183x over previous
//
#include <hip/hip_runtime.h>
#include <math.h>

#define B_SZ   2048
#define D_SZ   4096
#define NBASIS 8
#define TB     16            // batch rows per block
#define NC     16            // d-chunks (256 d per block)
#define DC     256           // d's per block (== blockDim)
#define NBG    (B_SZ / TB)   // 128 batch groups

// ws layout:
//   effc_t : NBASIS*D_SZ float4 = 524288 B   ([n][d], o in .x/.y/.z)
//   effb   : D_SZ float4        =  65536 B
//   partial: NC*B_SZ*3 float    = 393216 B
#define WS_EFFC_BYTES  (NBASIS * D_SZ * 16)
#define WS_EFFB_BYTES  (D_SZ * 16)
#define WS_PART_BYTES  (NC * B_SZ * 3 * 4)

// ---------------------------------------------------------------------------
__global__ __launch_bounds__(256) void precompute_eff(
    const float* __restrict__ coef, const float* __restrict__ sb,
    const float* __restrict__ ssp,  const float* __restrict__ mask,
    float4* __restrict__ effc_t, float4* __restrict__ effb)
{
    int d = blockIdx.x * 256 + threadIdx.x;
    if (d >= D_SZ) return;
    float m0 = mask[d*3+0], m1 = mask[d*3+1], m2 = mask[d*3+2];
    float s0 = ssp[d*3+0]*m0, s1 = ssp[d*3+1]*m1, s2 = ssp[d*3+2]*m2;
    #pragma unroll
    for (int n = 0; n < NBASIS; ++n) {
        float4 v;
        v.x = coef[(d*3+0)*NBASIS + n] * s0;
        v.y = coef[(d*3+1)*NBASIS + n] * s1;
        v.z = coef[(d*3+2)*NBASIS + n] * s2;
        v.w = 0.0f;
        effc_t[(size_t)n * D_SZ + d] = v;     // n-major: coalesced reads later
    }
    float4 bv;
    bv.x = sb[d*3+0]*m0; bv.y = sb[d*3+1]*m1; bv.z = sb[d*3+2]*m2; bv.w = 0.0f;
    effb[d] = bv;
}

// ---------------------------------------------------------------------------
// DPP wave-sum: result (sum of all 64 lanes) lands in lane 63. VALU pipe only.
template<int CTRL, int RMASK>
__device__ __forceinline__ float dpp_add(float v) {
    int x = __builtin_amdgcn_update_dpp(0, __float_as_int(v), CTRL, RMASK, 0xF, true);
    return v + __int_as_float(x);
}
__device__ __forceinline__ float wave_sum63(float v) {
    v = dpp_add<0x111, 0xF>(v);   // row_shr:1
    v = dpp_add<0x112, 0xF>(v);   // row_shr:2
    v = dpp_add<0x114, 0xF>(v);   // row_shr:4
    v = dpp_add<0x118, 0xF>(v);   // row_shr:8
    v = dpp_add<0x142, 0xA>(v);   // row_bcast:15 -> rows 1,3
    v = dpp_add<0x143, 0xC>(v);   // row_bcast:31 -> rows 2,3
    return v;                     // lane 63 = total
}

// ---------------------------------------------------------------------------
// Main kernel: zero-LDS main loop. Thread owns d; 24 coef floats in registers;
// dense 8-basis dot with cndmask-selected weights; DPP reduction tail.
__global__ __launch_bounds__(256) void kan_main(
    const float* __restrict__ x, const float4* __restrict__ effc_t,
    const float4* __restrict__ effb, const float* __restrict__ grid,
    float* __restrict__ partial)
{
    __shared__ float tail[48 * 4];         // 768 B: [i][wave]

    const int tid = threadIdx.x;
    const int bg  = blockIdx.x;            // 0..NBG-1
    const int dc  = blockIdx.y;            // 0..NC-1
    const int d   = dc * DC + tid;
    const int lane = tid & 63;
    const int wv   = tid >> 6;

    // ---- issue x loads first (deep VMEM queue) ----
    const int b0 = bg * TB;
    const float* xp = x + (size_t)b0 * D_SZ + d;
    float xv[TB];
    #pragma unroll
    for (int q = 0; q < TB; ++q) xv[q] = xp[(size_t)q * D_SZ];

    // ---- per-thread coef into registers (coalesced: n-major layout) ----
    float k0[NBASIS], k1[NBASIS], k2[NBASIS];
    #pragma unroll
    for (int n = 0; n < NBASIS; ++n) {
        float4 v = effc_t[(size_t)n * D_SZ + d];
        k0[n] = v.x; k1[n] = v.y; k2[n] = v.z;
    }
    const float4 eb = effb[d];
    const float g3   = grid[3];                     // -1
    const float invh = 1.0f / (grid[4] - grid[3]);  // 2.5

    float acc[TB][3];
    #pragma unroll
    for (int q = 0; q < TB; ++q) {
        float X = xv[q];
        float u   = (X - g3) * invh;
        float cfl = fminf(fmaxf(truncf(u), 0.0f), 4.0f);
        int   cell = (int)cfl;
        float t  = u - cfl;
        float t2 = t*t, t3 = t2*t;
        float w0 = fmaf(fmaf(fmaf(t, -1.0f/6.0f, 0.5f), t, -0.5f), t, 1.0f/6.0f);
        float w1 = fmaf(fmaf(t, 0.5f, -1.0f), t2, 2.0f/3.0f);
        float w3 = t3 * (1.0f/6.0f);
        float w2 = 1.0f - w0 - w1 - w3;
        float e   = __expf(-X);
        float sil = X * __builtin_amdgcn_rcpf(1.0f + e);

        // dense weight vector: wf[n] = w_{n-cell} if n-cell in [0,3] else 0
        bool m0c = (cell == 0), m1c = (cell == 1), m2c = (cell == 2),
             m3c = (cell == 3), m4c = (cell == 4);
        float wf0 = m0c ? w0 : 0.0f;
        float wf1 = m0c ? w1 : (m1c ? w0 : 0.0f);
        float wf2 = m0c ? w2 : (m1c ? w1 : (m2c ? w0 : 0.0f));
        float wf3 = m0c ? w3 : (m1c ? w2 : (m2c ? w1 : (m3c ? w0 : 0.0f)));
        float wf4 = m1c ? w3 : (m2c ? w2 : (m3c ? w1 : (m4c ? w0 : 0.0f)));
        float wf5 = m2c ? w3 : (m3c ? w2 : (m4c ? w1 : 0.0f));
        float wf6 = m3c ? w3 : (m4c ? w2 : 0.0f);
        float wf7 = m4c ? w3 : 0.0f;
        float wf[NBASIS] = {wf0, wf1, wf2, wf3, wf4, wf5, wf6, wf7};

        float a0 = sil * eb.x, a1 = sil * eb.y, a2 = sil * eb.z;
        #pragma unroll
        for (int n = 0; n < NBASIS; ++n) {
            a0 = fmaf(wf[n], k0[n], a0);
            a1 = fmaf(wf[n], k1[n], a1);
            a2 = fmaf(wf[n], k2[n], a2);
        }
        acc[q][0] = a0; acc[q][1] = a1; acc[q][2] = a2;
    }

    // ---- tail: DPP wave sums (VALU), tiny LDS to combine the 4 waves ----
    #pragma unroll
    for (int q = 0; q < TB; ++q)
        #pragma unroll
        for (int o = 0; o < 3; ++o) {
            float s = wave_sum63(acc[q][o]);
            if (lane == 63) tail[(q*3 + o)*4 + wv] = s;
        }
    __syncthreads();
    if (tid < 48) {
        float4 v = *(const float4*)&tail[tid*4];
        float s = (v.x + v.y) + (v.z + v.w);
        int q = tid / 3, o = tid % 3;
        partial[((size_t)dc * B_SZ + (b0 + q))*3 + o] = s;
    }
}

// ---------------------------------------------------------------------------
__global__ __launch_bounds__(256) void reduce_partials(
    const float* __restrict__ partial, float* __restrict__ out)
{
    int i = blockIdx.x * 256 + threadIdx.x;
    if (i >= B_SZ * 3) return;
    float s = 0.0f;
    #pragma unroll
    for (int c = 0; c < NC; ++c) s += partial[(size_t)c * B_SZ * 3 + i];
    out[i] = s;
}

// ---------------------------------------------------------------------------
// Fallback (no workspace): block per b, raw arrays. Slower but correct.
__global__ __launch_bounds__(256) void kan_fallback(
    const float* __restrict__ x, const float* __restrict__ grid,
    const float* __restrict__ coef, const float* __restrict__ sb,
    const float* __restrict__ ssp,  const float* __restrict__ mask,
    float* __restrict__ out)
{
    __shared__ float red[3][4];
    int b = blockIdx.x, tid = threadIdx.x;
    float g3 = grid[3], invh = 1.0f / (grid[4] - grid[3]);
    float acc[3] = {0.f, 0.f, 0.f};
    for (int i = 0; i < D_SZ / 256; ++i) {
        int d = i * 256 + tid;
        float xv = x[(size_t)b * D_SZ + d];
        float u  = (xv - g3) * invh;
        float cfl = floorf(u);
        cfl = fminf(fmaxf(cfl, 0.0f), 4.0f);
        int  cell = (int)cfl;
        float t  = u - cfl;
        float t2 = t * t, t3 = t2 * t;
        float omt = 1.0f - t;
        float w0 = omt*omt*omt * (1.0f/6.0f);
        float w1 = (3.0f*t3 - 6.0f*t2 + 4.0f) * (1.0f/6.0f);
        float w2 = (-3.0f*t3 + 3.0f*t2 + 3.0f*t + 1.0f) * (1.0f/6.0f);
        float w3 = t3 * (1.0f/6.0f);
        float sil = xv / (1.0f + __expf(-xv));
        #pragma unroll
        for (int o = 0; o < 3; ++o) {
            const float* cp = &coef[(d*3 + o) * NBASIS + cell];
            float s = w0*cp[0] + w1*cp[1] + w2*cp[2] + w3*cp[3];
            float m = mask[d*3 + o];
            acc[o] += s * ssp[d*3 + o] * m + sil * sb[d*3 + o] * m;
        }
    }
    int lane = tid & 63, wv = tid >> 6;
    #pragma unroll
    for (int o = 0; o < 3; ++o) {
        float v = acc[o];
        #pragma unroll
        for (int off = 32; off >= 1; off >>= 1) v += __shfl_down(v, off, 64);
        if (lane == 0) red[o][wv] = v;
    }
    __syncthreads();
    if (tid < 3) {
        float s = red[tid][0] + red[tid][1] + red[tid][2] + red[tid][3];
        out[b * 3 + tid] = s;
    }
}

// ---------------------------------------------------------------------------
extern "C" void kernel_launch(void* const* d_in, const int* in_sizes, int n_in,
                              void* d_out, int out_size, void* d_ws, size_t ws_size,
                              hipStream_t stream)
{
    const float* x    = (const float*)d_in[0];
    const float* grid = (const float*)d_in[4];
    const float* coef = (const float*)d_in[5];
    const float* sb   = (const float*)d_in[6];
    const float* ssp  = (const float*)d_in[7];
    const float* mask = (const float*)d_in[8];
    float* out = (float*)d_out;

    size_t need = (size_t)WS_EFFC_BYTES + WS_EFFB_BYTES + WS_PART_BYTES;
    if (ws_size >= need) {
        float4* effc_t  = (float4*)d_ws;
        float4* effb    = (float4*)((char*)d_ws + WS_EFFC_BYTES);
        float*  partial = (float*)((char*)d_ws + WS_EFFC_BYTES + WS_EFFB_BYTES);

        precompute_eff<<<D_SZ/256, 256, 0, stream>>>(coef, sb, ssp, mask, effc_t, effb);
        dim3 g(NBG, NC);
        kan_main<<<g, 256, 0, stream>>>(x, effc_t, effb, grid, partial);
        reduce_partials<<<(B_SZ*3 + 255)/256, 256, 0, stream>>>(partial, out);
    } else {
        kan_fallback<<<B_SZ, 256, 0, stream>>>(x, grid, coef, sb, ssp, mask, out);
    }
}

// Round 6
// 26.886 us; speedup vs baseline: 2.1657x; 1.2604x over previous
//
#include <hip/hip_runtime.h>
#include <math.h>

#define B_SZ   2048
#define D_SZ   4096
#define NBASIS 8
#define TB     16            // batch rows per block
#define NC     16            // d-chunks (256 d per block)
#define DC     256           // d's per block (== blockDim)
#define NBG    (B_SZ / TB)   // 128 batch groups

// ws layout:
//   effc_p : NBASIS*3*D_SZ float = 393216 B   (planar [n][o][d])
//   effb   : D_SZ float4         =  65536 B
//   partial: NC*B_SZ*3 float     = 393216 B
#define WS_EFFC_BYTES  (NBASIS * 3 * D_SZ * 4)
#define WS_EFFB_BYTES  (D_SZ * 16)
#define WS_PART_BYTES  (NC * B_SZ * 3 * 4)

// ---------------------------------------------------------------------------
__global__ __launch_bounds__(256) void precompute_eff(
    const float* __restrict__ coef, const float* __restrict__ sb,
    const float* __restrict__ ssp,  const float* __restrict__ mask,
    float* __restrict__ effc_p, float4* __restrict__ effb)
{
    int d = blockIdx.x * 256 + threadIdx.x;
    if (d >= D_SZ) return;
    float m0 = mask[d*3+0], m1 = mask[d*3+1], m2 = mask[d*3+2];
    float s0 = ssp[d*3+0]*m0, s1 = ssp[d*3+1]*m1, s2 = ssp[d*3+2]*m2;
    #pragma unroll
    for (int n = 0; n < NBASIS; ++n) {
        effc_p[(size_t)(n*3 + 0) * D_SZ + d] = coef[(d*3+0)*NBASIS + n] * s0;
        effc_p[(size_t)(n*3 + 1) * D_SZ + d] = coef[(d*3+1)*NBASIS + n] * s1;
        effc_p[(size_t)(n*3 + 2) * D_SZ + d] = coef[(d*3+2)*NBASIS + n] * s2;
    }
    float4 bv;
    bv.x = sb[d*3+0]*m0; bv.y = sb[d*3+1]*m1; bv.z = sb[d*3+2]*m2; bv.w = 0.0f;
    effb[d] = bv;
}

// ---------------------------------------------------------------------------
// DPP 16-lane-group suffix sum: lane 15 of each 16-lane row holds the row sum.
template<int CTRL>
__device__ __forceinline__ float dpp_add(float v) {
    int x = __builtin_amdgcn_update_dpp(0, __float_as_int(v), CTRL, 0xF, 0xF, true);
    return v + __int_as_float(x);
}
__device__ __forceinline__ float group16_sum(float v) {
    v = dpp_add<0x111>(v);   // row_shr:1
    v = dpp_add<0x112>(v);   // row_shr:2
    v = dpp_add<0x114>(v);   // row_shr:4
    v = dpp_add<0x118>(v);   // row_shr:8
    return v;                // lane 15 (mod 16) = sum of its 16-lane row
}

// ---------------------------------------------------------------------------
// Main kernel: conflict-free LDS b32 gather (bank = tid%32 independent of cell),
// 12 FMA dot, 4-step DPP tail + small LDS combine.
__global__ __launch_bounds__(256) void kan_main(
    const float* __restrict__ x, const float* __restrict__ effc_p,
    const float4* __restrict__ effb, const float* __restrict__ grid,
    float* __restrict__ partial)
{
    __shared__ float lds_k[NBASIS * 3 * DC];   // 24 KB planar [n][o][256]
    __shared__ float tl[48 * 16];              // 3 KB tail combine

    const int tid = threadIdx.x;
    const int bg  = blockIdx.x;            // 0..NBG-1
    const int dc  = blockIdx.y;            // 0..NC-1
    const int d   = dc * DC + tid;
    const int lane = tid & 63;

    // ---- stage coef planes: 24 coalesced b32 loads, 2-way-free LDS writes ----
    #pragma unroll
    for (int p = 0; p < NBASIS * 3; ++p)
        lds_k[p * DC + tid] = effc_p[(size_t)p * D_SZ + d];

    const float4 eb  = effb[d];
    const float g3   = grid[3];                     // -1
    const float invh = 1.0f / (grid[4] - grid[3]);  // 2.5
    __syncthreads();

    const int b0 = bg * TB;
    const float* xp = x + (size_t)b0 * D_SZ + d;
    float xv[TB];
    #pragma unroll
    for (int q = 0; q < TB; ++q) xv[q] = xp[(size_t)q * D_SZ];

    #pragma unroll
    for (int q = 0; q < TB; ++q) {
        float X = xv[q];
        float u   = (X - g3) * invh;
        float cfl = fminf(fmaxf(truncf(u), 0.0f), 4.0f);
        int   cell = (int)cfl;
        float t  = u - cfl;
        float t2 = t*t, t3 = t2*t;
        float w[4];
        w[0] = fmaf(fmaf(fmaf(t, -1.0f/6.0f, 0.5f), t, -0.5f), t, 1.0f/6.0f);
        w[1] = fmaf(fmaf(t, 0.5f, -1.0f), t2, 2.0f/3.0f);
        w[3] = t3 * (1.0f/6.0f);
        w[2] = 1.0f - w[0] - w[1] - w[3];
        float e   = __expf(-X);
        float sil = X * __builtin_amdgcn_rcpf(1.0f + e);

        // gather: word = cell*768 + tid + (j*3+o)*256; 768 % 32 == 0 so the
        // bank is tid%32 for every lane regardless of cell -> 2-way (free).
        const float* kp = &lds_k[cell * 768 + tid];
        float a0 = sil * eb.x, a1 = sil * eb.y, a2 = sil * eb.z;
        #pragma unroll
        for (int j = 0; j < 4; ++j) {
            a0 = fmaf(w[j], kp[(j*3 + 0) * DC], a0);
            a1 = fmaf(w[j], kp[(j*3 + 1) * DC], a1);
            a2 = fmaf(w[j], kp[(j*3 + 2) * DC], a2);
        }

        // ---- tail (fusable per-q: no barrier needed, separate LDS region) ----
        float s0 = group16_sum(a0);
        float s1 = group16_sum(a1);
        float s2 = group16_sum(a2);
        if ((lane & 15) == 15) {
            int g = tid >> 4;              // 0..15 unique per writer
            tl[(q*3 + 0)*16 + g] = s0;
            tl[(q*3 + 1)*16 + g] = s1;
            tl[(q*3 + 2)*16 + g] = s2;
        }
    }

    __syncthreads();
    if (tid < 48) {
        const float4* v = (const float4*)&tl[tid * 16];
        float4 v0 = v[0], v1 = v[1], v2 = v[2], v3 = v[3];
        float s = ((v0.x+v0.y)+(v0.z+v0.w)) + ((v1.x+v1.y)+(v1.z+v1.w))
                + ((v2.x+v2.y)+(v2.z+v2.w)) + ((v3.x+v3.y)+(v3.z+v3.w));
        int q = tid / 3, o = tid % 3;
        partial[((size_t)dc * B_SZ + (b0 + q))*3 + o] = s;
    }
}

// ---------------------------------------------------------------------------
__global__ __launch_bounds__(256) void reduce_partials(
    const float* __restrict__ partial, float* __restrict__ out)
{
    int i = blockIdx.x * 256 + threadIdx.x;
    if (i >= B_SZ * 3) return;
    float s = 0.0f;
    #pragma unroll
    for (int c = 0; c < NC; ++c) s += partial[(size_t)c * B_SZ * 3 + i];
    out[i] = s;
}

// ---------------------------------------------------------------------------
// Fallback (no workspace): block per b, raw arrays. Slower but correct.
__global__ __launch_bounds__(256) void kan_fallback(
    const float* __restrict__ x, const float* __restrict__ grid,
    const float* __restrict__ coef, const float* __restrict__ sb,
    const float* __restrict__ ssp,  const float* __restrict__ mask,
    float* __restrict__ out)
{
    __shared__ float red[3][4];
    int b = blockIdx.x, tid = threadIdx.x;
    float g3 = grid[3], invh = 1.0f / (grid[4] - grid[3]);
    float acc[3] = {0.f, 0.f, 0.f};
    for (int i = 0; i < D_SZ / 256; ++i) {
        int d = i * 256 + tid;
        float xv = x[(size_t)b * D_SZ + d];
        float u  = (xv - g3) * invh;
        float cfl = floorf(u);
        cfl = fminf(fmaxf(cfl, 0.0f), 4.0f);
        int  cell = (int)cfl;
        float t  = u - cfl;
        float t2 = t * t, t3 = t2 * t;
        float omt = 1.0f - t;
        float w0 = omt*omt*omt * (1.0f/6.0f);
        float w1 = (3.0f*t3 - 6.0f*t2 + 4.0f) * (1.0f/6.0f);
        float w2 = (-3.0f*t3 + 3.0f*t2 + 3.0f*t + 1.0f) * (1.0f/6.0f);
        float w3 = t3 * (1.0f/6.0f);
        float sil = xv / (1.0f + __expf(-xv));
        #pragma unroll
        for (int o = 0; o < 3; ++o) {
            const float* cp = &coef[(d*3 + o) * NBASIS + cell];
            float s = w0*cp[0] + w1*cp[1] + w2*cp[2] + w3*cp[3];
            float m = mask[d*3 + o];
            acc[o] += s * ssp[d*3 + o] * m + sil * sb[d*3 + o] * m;
        }
    }
    int lane = tid & 63, wv = tid >> 6;
    #pragma unroll
    for (int o = 0; o < 3; ++o) {
        float v = acc[o];
        #pragma unroll
        for (int off = 32; off >= 1; off >>= 1) v += __shfl_down(v, off, 64);
        if (lane == 0) red[o][wv] = v;
    }
    __syncthreads();
    if (tid < 3) {
        float s = red[tid][0] + red[tid][1] + red[tid][2] + red[tid][3];
        out[b * 3 + tid] = s;
    }
}

// ---------------------------------------------------------------------------
extern "C" void kernel_launch(void* const* d_in, const int* in_sizes, int n_in,
                              void* d_out, int out_size, void* d_ws, size_t ws_size,
                              hipStream_t stream)
{
    const float* x    = (const float*)d_in[0];
    const float* grid = (const float*)d_in[4];
    const float* coef = (const float*)d_in[5];
    const float* sb   = (const float*)d_in[6];
    const float* ssp  = (const float*)d_in[7];
    const float* mask = (const float*)d_in[8];
    float* out = (float*)d_out;

    size_t need = (size_t)WS_EFFC_BYTES + WS_EFFB_BYTES + WS_PART_BYTES;
    if (ws_size >= need) {
        float*  effc_p  = (float*)d_ws;
        float4* effb    = (float4*)((char*)d_ws + WS_EFFC_BYTES);
        float*  partial = (float*)((char*)d_ws + WS_EFFC_BYTES + WS_EFFB_BYTES);

        precompute_eff<<<D_SZ/256, 256, 0, stream>>>(coef, sb, ssp, mask, effc_p, effb);
        dim3 g(NBG, NC);
        kan_main<<<g, 256, 0, stream>>>(x, effc_p, effb, grid, partial);
        reduce_partials<<<(B_SZ*3 + 255)/256, 256, 0, stream>>>(partial, out);
    } else {
        kan_fallback<<<B_SZ, 256, 0, stream>>>(x, grid, coef, sb, ssp, mask, out);
    }
}